// Round 4
// baseline (265.833 us; speedup 1.0000x reference)
//
#include <hip/hip_runtime.h>
#include <stdint.h>

#define T_STEPS 2048
#define LARGEF  1.0e9f
typedef unsigned long long u64;
typedef unsigned uint2v __attribute__((ext_vector_type(2)));

__device__ __forceinline__ int par6(int x) { return __builtin_popcount((unsigned)x) & 1; }

constexpr int CARR[6] = {5, 6, 12, 8, 16, 32};
constexpr int MARR[6] = {1, 2, 7, 15, 16, 32};

constexpr u64 ptab_gen(int C) {
  u64 r = 0;
  for (int s = 0; s < 64; ++s) r |= (u64)(__builtin_popcount((unsigned)(s & C)) & 1) << s;
  return r;
}
constexpr u64 PTAB[6] = {ptab_gen(5), ptab_gen(6), ptab_gen(12),
                         ptab_gen(8), ptab_gen(16), ptab_gen(32)};

template<int CTRL>
__device__ __forceinline__ float xdpp(float x) {
  return __int_as_float(__builtin_amdgcn_update_dpp(0, __float_as_int(x), CTRL, 0xF, 0xF, true));
}

__device__ __forceinline__ float exch16(float x, bool use_rx) {
#if __has_builtin(__builtin_amdgcn_permlane16_swap)
  uint2v r = __builtin_amdgcn_permlane16_swap(__float_as_uint(x), __float_as_uint(x), false, false);
  return __uint_as_float(use_rx ? r.x : r.y);
#else
  (void)use_rx;
  return __int_as_float(__builtin_amdgcn_ds_swizzle(__float_as_int(x), 0x401F));
#endif
}
__device__ __forceinline__ float exch32(float x, bool use_rx) {
#if __has_builtin(__builtin_amdgcn_permlane32_swap)
  uint2v r = __builtin_amdgcn_permlane32_swap(__float_as_uint(x), __float_as_uint(x), false, false);
  return __uint_as_float(use_rx ? r.x : r.y);
#else
  (void)use_rx;
  return __shfl_xor(x, 32, 64);
#endif
}

struct Ctx {
  float sae[6], sbe[6];
  bool pd[6];
  bool use_rx16, use_rx32;
};

// ---- forward: 16 steps, 2 interleaved batches; bit K+OFF of w = survivor LSB ----
template<int SP, int OFF, int K>
__device__ __forceinline__ void fwd16(float& cumA, float& cumB, unsigned& wA, unsigned& wB,
                                      const float4 (&fa)[8], const float4 (&fb)[8],
                                      const Ctx& cx) {
  if constexpr (K < 16) {
    constexpr int ph = (SP + K) % 6;
    const float4 qa = fa[K >> 1];
    const float4 qb = fb[K >> 1];
    const float y0A = (K & 1) ? qa.z : qa.x;
    const float y1A = (K & 1) ? qa.w : qa.y;
    const float y0B = (K & 1) ? qb.z : qb.x;
    const float y1B = (K & 1) ? qb.w : qb.y;
    const float bmA = fmaf(cx.sae[ph], y0A, cx.sbe[ph] * y1A);   // bit-exact vs ref
    const float bmB = fmaf(cx.sae[ph], y0B, cx.sbe[ph] * y1B);
    float exA, exB;
    if constexpr (ph == 0)      { exA = xdpp<0xB1>(cumA);  exB = xdpp<0xB1>(cumB); }
    else if constexpr (ph == 1) { exA = xdpp<0x4E>(cumA);  exB = xdpp<0x4E>(cumB); }
    else if constexpr (ph == 2) { exA = xdpp<0x141>(cumA); exB = xdpp<0x141>(cumB); }
    else if constexpr (ph == 3) { exA = xdpp<0x140>(cumA); exB = xdpp<0x140>(cumB); }
    else if constexpr (ph == 4) { exA = exch16(cumA, cx.use_rx16); exB = exch16(cumB, cx.use_rx16); }
    else                        { exA = exch32(cumA, cx.use_rx32); exB = exch32(cumB, cx.use_rx32); }
    const float cAA = cumA + bmA;
    const float cBA = exA - bmA;
    const float cAB = cumB + bmB;
    const float cBB = exB - bmB;
    // survivor LSB; tie -> even predecessor (matches argmin-first in ref)
    const bool bitA = cx.pd[ph] ? (cAA < cBA) : (cBA < cAA);
    const bool bitB = cx.pd[ph] ? (cAB < cBB) : (cBB < cAB);
    wA |= ((unsigned)bitA) << (OFF + K);
    wB |= ((unsigned)bitB) << (OFF + K);
    cumA = fminf(cAA, cBA);
    cumB = fminf(cAB, cBB);
    fwd16<SP, OFF, K + 1>(cumA, cumB, wA, wB, fa, fb, cx);
  }
}

// ---- traceback: 32 steps descending, 2 interleaved uniform scalar chains ----
template<int SP, int K>
__device__ __forceinline__ void tb32(int& lamA, int& lamB, unsigned rA, unsigned rB,
                                     unsigned& oA, unsigned& oB) {
  if constexpr (K >= 0) {
    constexpr int ph = (SP + K) % 6;
    const int jA = (__builtin_amdgcn_readlane((int)rA, lamA) >> K) & 1;
    const int jB = (__builtin_amdgcn_readlane((int)rB, lamB) >> K) & 1;
    const int ccA = (int)((PTAB[ph] >> lamA) & 1);
    const int ccB = (int)((PTAB[ph] >> lamB) & 1);
    oA |= ((unsigned)ccA) << K;
    oB |= ((unsigned)ccB) << K;
    lamA ^= (ccA ^ jA) ? MARR[ph] : 0;
    lamB ^= (ccB ^ jB) ? MARR[ph] : 0;
    tb32<SP, K - 1>(lamA, lamB, rA, rB, oA, oB);
  }
}

__global__ __launch_bounds__(64, 1) void viterbi_kernel(const float* __restrict__ in,
                                                        float* __restrict__ out) {
  __shared__ float yA[2 * T_STEPS], yB[2 * T_STEPS];     // 32 KB staged rows
  __shared__ unsigned tbA[T_STEPS * 2], tbB[T_STEPS * 2]; // 32 KB decision words

  const int lane = threadIdx.x;
  const int b0 = 2 * blockIdx.x, b1 = b0 + 1;

  // ---- stage both rows (coalesced float4) ----
  {
    const float4* gA = (const float4*)(in + (size_t)b0 * (2 * T_STEPS));
    const float4* gB = (const float4*)(in + (size_t)b1 * (2 * T_STEPS));
    float4* lA = (float4*)yA;
    float4* lB = (float4*)yB;
#pragma unroll
    for (int i = 0; i < 16; ++i) {
      lA[i * 64 + lane] = gA[i * 64 + lane];
      lB[i * 64 + lane] = gB[i * 64 + lane];
    }
  }
  __syncthreads();

  // ---- per-phase lane constants (shared by both batches) ----
  Ctx cx;
#pragma unroll
  for (int ph = 0; ph < 6; ++ph) {
    const int pdv = par6(lane & CARR[ph]);
    int t = 0;
#pragma unroll
    for (int j = 0; j < 5; ++j) t |= par6(lane & CARR[(ph + 1 + j) % 6]) << j;
    t |= pdv << 5;
    const float sa = 1.0f - 2.0f * (float)par6(t & 45);   // poly 1011011
    const float sb = 1.0f - 2.0f * (float)par6(t & 60);   // poly 1111001
    cx.sae[ph] = pdv ? -sa : sa;
    cx.sbe[ph] = pdv ? -sb : sb;
    cx.pd[ph] = (pdv != 0);
  }
  // ---- probe permlane swap output-register convention ----
  {
    const bool oddrow = ((lane >> 4) & 1) != 0;
    const bool lanehi = lane >= 32;
#if __has_builtin(__builtin_amdgcn_permlane16_swap)
    uint2v p16 = __builtin_amdgcn_permlane16_swap((unsigned)lane, (unsigned)lane, false, false);
    const bool rxo = ((unsigned)__builtin_amdgcn_readlane((int)p16.x, 0) == 16u);
    cx.use_rx16 = oddrow ^ rxo;
#else
    cx.use_rx16 = false;
#endif
#if __has_builtin(__builtin_amdgcn_permlane32_swap)
    uint2v p32 = __builtin_amdgcn_permlane32_swap((unsigned)lane, (unsigned)lane, false, false);
    const bool rxh = ((unsigned)__builtin_amdgcn_readlane((int)p32.x, 0) == 32u);
    cx.use_rx32 = lanehi ^ rxh;
#else
    cx.use_rx32 = false;
#endif
  }

  // ---- forward ACS: 128 bodies of 16 steps; body start phase (16h)%6 cycles [0,4,2] ----
  float cumA = (lane == 0) ? 0.0f : LARGEF;
  float cumB = (lane == 0) ? 0.0f : LARGEF;
  unsigned wA = 0, wB = 0, loA = 0, loB = 0;
  int m6 = 0;
  for (int h = 0; h < 128; ++h) {
    float4 fa[8], fb[8];
    const float4* pa = ((const float4*)yA) + 8 * h;
    const float4* pb = ((const float4*)yB) + 8 * h;
#pragma unroll
    for (int j = 0; j < 8; ++j) { fa[j] = pa[j]; fb[j] = pb[j]; }
    switch (m6) {
      case 0: fwd16<0, 0, 0>(cumA, cumB, wA, wB, fa, fb, cx); break;
      case 1: fwd16<4, 16, 0>(cumA, cumB, wA, wB, fa, fb, cx); break;
      case 2: fwd16<2, 0, 0>(cumA, cumB, wA, wB, fa, fb, cx); break;
      case 3: fwd16<0, 16, 0>(cumA, cumB, wA, wB, fa, fb, cx); break;
      case 4: fwd16<4, 0, 0>(cumA, cumB, wA, wB, fa, fb, cx); break;
      default: fwd16<2, 16, 0>(cumA, cumB, wA, wB, fa, fb, cx); break;
    }
    m6 = (m6 == 5) ? 0 : m6 + 1;
    if (h & 1) {
      if ((h & 3) == 1) { loA = wA; loB = wB; }
      else {
        const int c = h >> 2;
        tbA[(c * 64 + lane) * 2] = loA;  tbA[(c * 64 + lane) * 2 + 1] = wA;
        tbB[(c * 64 + lane) * 2] = loB;  tbB[(c * 64 + lane) * 2 + 1] = wB;
      }
      wA = 0; wB = 0;
    }
  }
  __syncthreads();

  // ---- terminal argmin over true states (tie -> smallest state) ----
  // final labeling = phase 2048%6 = 2: state bit j from C[(2+j)%6] = {12,8,16,32,5,6}
  const int stf = par6(lane & 12) | (par6(lane & 8) << 1) | (par6(lane & 16) << 2) |
                  (par6(lane & 32) << 3) | (par6(lane & 5) << 4) | (par6(lane & 6) << 5);
  float vA = cumA, vB = cumB;
  int bsA = stf, bsB = stf, blA = lane, blB = lane;
#pragma unroll
  for (int off = 32; off >= 1; off >>= 1) {
    const float ovA = __shfl_xor(vA, off, 64);
    const int osA = __shfl_xor(bsA, off, 64);
    const int olA = __shfl_xor(blA, off, 64);
    const float ovB = __shfl_xor(vB, off, 64);
    const int osB = __shfl_xor(bsB, off, 64);
    const int olB = __shfl_xor(blB, off, 64);
    if (ovA < vA || (ovA == vA && osA < bsA)) { vA = ovA; bsA = osA; blA = olA; }
    if (ovB < vB || (ovB == vB && osB < bsB)) { vB = ovB; bsB = osB; blB = olB; }
  }
  int lamA = __builtin_amdgcn_readfirstlane(blA);
  int lamB = __builtin_amdgcn_readfirstlane(blB);

  // ---- traceback: 32 chunks, halves hi then lo; two interleaved scalar chains ----
  const size_t obA = (size_t)b0 * T_STEPS;
  const size_t obB = (size_t)b1 * T_STEPS;
  unsigned rloA = tbA[(31 * 64 + lane) * 2], rhiA = tbA[(31 * 64 + lane) * 2 + 1];
  unsigned rloB = tbB[(31 * 64 + lane) * 2], rhiB = tbB[(31 * 64 + lane) * 2 + 1];
  int cm3 = 1;  // 31 % 3
  for (int c = 31; c >= 0; --c) {
    unsigned nloA = 0, nhiA = 0, nloB = 0, nhiB = 0;
    if (c > 0) {  // prefetch next chunk (addresses independent of lam)
      nloA = tbA[((c - 1) * 64 + lane) * 2]; nhiA = tbA[((c - 1) * 64 + lane) * 2 + 1];
      nloB = tbB[((c - 1) * 64 + lane) * 2]; nhiB = tbB[((c - 1) * 64 + lane) * 2 + 1];
    }
    unsigned oblA = 0, obhA = 0, oblB = 0, obhB = 0;
    if (cm3 == 0)      { tb32<2, 31>(lamA, lamB, rhiA, rhiB, obhA, obhB);
                         tb32<0, 31>(lamA, lamB, rloA, rloB, oblA, oblB); }
    else if (cm3 == 1) { tb32<0, 31>(lamA, lamB, rhiA, rhiB, obhA, obhB);
                         tb32<4, 31>(lamA, lamB, rloA, rloB, oblA, oblB); }
    else               { tb32<4, 31>(lamA, lamB, rhiA, rhiB, obhA, obhB);
                         tb32<2, 31>(lamA, lamB, rloA, rloB, oblA, oblB); }
    cm3 = (cm3 == 0) ? 2 : cm3 - 1;
    const unsigned wordA = (lane >= 32) ? obhA : oblA;
    const unsigned wordB = (lane >= 32) ? obhB : oblB;
    out[obA + c * 64 + lane] = (float)((wordA >> (lane & 31)) & 1u);
    out[obB + c * 64 + lane] = (float)((wordB >> (lane & 31)) & 1u);
    rloA = nloA; rhiA = nhiA; rloB = nloB; rhiB = nhiB;
  }
}

extern "C" void kernel_launch(void* const* d_in, const int* in_sizes, int n_in,
                              void* d_out, int out_size, void* d_ws, size_t ws_size,
                              hipStream_t stream) {
  const float* in = (const float*)d_in[0];
  float* out = (float*)d_out;
  (void)in_sizes; (void)n_in; (void)out_size; (void)d_ws; (void)ws_size;
  viterbi_kernel<<<dim3(256), dim3(64), 0, stream>>>(in, out);
}

// Round 5
// 85.576 us; speedup vs baseline: 3.1064x; 3.1064x over previous
//
#include <hip/hip_runtime.h>
#include <stdint.h>

#define T_STEPS 2048
#define NCHUNK  86            // 85 full 24-step chunks + one 8-step tail chunk
#define LARGEF  1.0e9f
typedef unsigned long long u64;
typedef unsigned uint2v __attribute__((ext_vector_type(2)));

__device__ __forceinline__ int par6(int x) { return __builtin_popcount((unsigned)x) & 1; }

// dual-basis functionals C and exchange masks m (algebra verified rounds 2-4)
constexpr int CARR[6] = {5, 6, 12, 8, 16, 32};

template<int CTRL>
__device__ __forceinline__ float xdpp(float x) {
  return __int_as_float(__builtin_amdgcn_update_dpp(0, __float_as_int(x), CTRL, 0xF, 0xF, true));
}
template<int CTRL>
__device__ __forceinline__ unsigned xdpp_u(unsigned x) {
  return (unsigned)__builtin_amdgcn_update_dpp(0, (int)x, CTRL, 0xF, 0xF, true);
}

__device__ __forceinline__ unsigned exch16_u(unsigned x, bool use_rx) {
#if __has_builtin(__builtin_amdgcn_permlane16_swap)
  uint2v r = __builtin_amdgcn_permlane16_swap(x, x, false, false);
  return use_rx ? r.x : r.y;
#else
  (void)use_rx;
  return (unsigned)__builtin_amdgcn_ds_swizzle((int)x, 0x401F);
#endif
}
__device__ __forceinline__ unsigned exch32_u(unsigned x, bool use_rx) {
#if __has_builtin(__builtin_amdgcn_permlane32_swap)
  uint2v r = __builtin_amdgcn_permlane32_swap(x, x, false, false);
  return use_rx ? r.x : r.y;
#else
  (void)use_rx;
  return (unsigned)__shfl_xor((int)x, 32, 64);
#endif
}
__device__ __forceinline__ float exch16f(float x, bool use_rx) {
  return __uint_as_float(exch16_u(__float_as_uint(x), use_rx));
}
__device__ __forceinline__ float exch32f(float x, bool use_rx) {
  return __uint_as_float(exch32_u(__float_as_uint(x), use_rx));
}

struct Ctx {
  float sae[6], sbe[6];
  unsigned pdu[6];   // decoded-bit constant per phase (0/1)
  bool pd[6];        // own-pred LSB parity (tie semantics)
  bool use_rx16, use_rx32;
};

// ---- one chunk of N steps (N=24 or 8), start phase 0; word = [path bits 6..][anc 0..5] ----
template<int N, int K>
__device__ __forceinline__ void fchunk(float& cum, unsigned& word,
                                       const float4 (&fy)[12], const Ctx& cx) {
  if constexpr (K < N) {
    constexpr int ph = K % 6;
    const float4 q = fy[K >> 1];
    const float y0 = (K & 1) ? q.z : q.x;
    const float y1 = (K & 1) ? q.w : q.y;
    const float bm = fmaf(cx.sae[ph], y0, cx.sbe[ph] * y1);   // bit-exact vs ref
    float ex; unsigned exw;
    if constexpr (ph == 0)      { ex = xdpp<0xB1>(cum);  exw = xdpp_u<0xB1>(word); }   // xor 1
    else if constexpr (ph == 1) { ex = xdpp<0x4E>(cum);  exw = xdpp_u<0x4E>(word); }   // xor 2
    else if constexpr (ph == 2) { ex = xdpp<0x141>(cum); exw = xdpp_u<0x141>(word); }  // xor 7
    else if constexpr (ph == 3) { ex = xdpp<0x140>(cum); exw = xdpp_u<0x140>(word); }  // xor 15
    else if constexpr (ph == 4) { ex = exch16f(cum, cx.use_rx16); exw = exch16_u(word, cx.use_rx16); } // xor 16
    else                        { ex = exch32f(cum, cx.use_rx32); exw = exch32_u(word, cx.use_rx32); } // xor 32
    const float cA = cum + bm;    // own-pred candidate
    const float cB = ex - bm;     // partner-pred candidate
    // take partner: strictly-better if own pred is even (tie->own), >= if own pred odd (tie->partner)
    const bool tp = cx.pd[ph] ? !(cA < cB) : (cB < cA);
    word = (tp ? exw : word) | (cx.pdu[ph] << (6 + K));   // select ancestor path, append own bit
    cum = fminf(cA, cB);
    fchunk<N, K + 1>(cum, word, fy, cx);
  }
}

__global__ __launch_bounds__(64, 1) void viterbi_kernel(const float* __restrict__ in,
                                                        float* __restrict__ out) {
  __shared__ float y_lds[2 * T_STEPS];     // 16 KB staged input row
  __shared__ unsigned tbf[NCHUNK * 64];    // 21.5 KB flushed path/anc words

  const int b = blockIdx.x;
  const int lane = threadIdx.x;
  const float* yrow = in + (size_t)b * (2 * T_STEPS);

  // ---- stage y into LDS (coalesced float4) ----
  {
    const float4* g = (const float4*)yrow;
    float4* l = (float4*)y_lds;
#pragma unroll
    for (int i = 0; i < 16; ++i) l[i * 64 + lane] = g[i * 64 + lane];
  }
  __syncthreads();

  // ---- per-phase lane constants ----
  Ctx cx;
#pragma unroll
  for (int ph = 0; ph < 6; ++ph) {
    const int pdv = par6(lane & CARR[ph]);
    int t = 0;
#pragma unroll
    for (int j = 0; j < 5; ++j) t |= par6(lane & CARR[(ph + 1 + j) % 6]) << j;
    t |= pdv << 5;
    const float sa = 1.0f - 2.0f * (float)par6(t & 45);   // poly 1011011
    const float sb = 1.0f - 2.0f * (float)par6(t & 60);   // poly 1111001
    cx.sae[ph] = pdv ? -sa : sa;
    cx.sbe[ph] = pdv ? -sb : sb;
    cx.pd[ph] = (pdv != 0);
    cx.pdu[ph] = (unsigned)pdv;
  }
  // ---- probe permlane swap output-register convention ----
  {
    const bool oddrow = ((lane >> 4) & 1) != 0;
    const bool lanehi = lane >= 32;
#if __has_builtin(__builtin_amdgcn_permlane16_swap)
    uint2v p16 = __builtin_amdgcn_permlane16_swap((unsigned)lane, (unsigned)lane, false, false);
    const bool rxo = ((unsigned)__builtin_amdgcn_readlane((int)p16.x, 0) == 16u);
    cx.use_rx16 = oddrow ^ rxo;
#else
    cx.use_rx16 = false;
#endif
#if __has_builtin(__builtin_amdgcn_permlane32_swap)
    uint2v p32 = __builtin_amdgcn_permlane32_swap((unsigned)lane, (unsigned)lane, false, false);
    const bool rxh = ((unsigned)__builtin_amdgcn_readlane((int)p32.x, 0) == 32u);
    cx.use_rx32 = lanehi ^ rxh;
#else
    cx.use_rx32 = false;
#endif
  }

  // ---- forward ACS with register-exchange path/ancestor words ----
  float cum = (lane == 0) ? 0.0f : LARGEF;
  unsigned word = (unsigned)lane;
  for (int c = 0; c < 85; ++c) {
    float4 fy[12];
    const float4* p = ((const float4*)y_lds) + 12 * c;
#pragma unroll
    for (int j = 0; j < 12; ++j) fy[j] = p[j];
    fchunk<24, 0>(cum, word, fy, cx);
    tbf[c * 64 + lane] = word;
    word = (unsigned)lane;
  }
  {  // tail chunk: 8 steps (2040..2047), starts at phase 0 (2040%6==0)
    float4 fy[12];
    const float4* p = ((const float4*)y_lds) + 1020;
#pragma unroll
    for (int j = 0; j < 4; ++j) fy[j] = p[j];
    fchunk<8, 0>(cum, word, fy, cx);
    tbf[85 * 64 + lane] = word;
  }
  __syncthreads();

  // ---- terminal argmin over true states (tie -> smallest state) ----
  // final labeling = phase 2048%6 = 2: state bit j from C[(2+j)%6] = {12,8,16,32,5,6}
  const int stf = par6(lane & 12) | (par6(lane & 8) << 1) | (par6(lane & 16) << 2) |
                  (par6(lane & 32) << 3) | (par6(lane & 5) << 4) | (par6(lane & 6) << 5);
  float v = cum; int bs = stf; int bl = lane;
#pragma unroll
  for (int off = 32; off >= 1; off >>= 1) {
    const float ov = __shfl_xor(v, off, 64);
    const int os = __shfl_xor(bs, off, 64);
    const int ol = __shfl_xor(bl, off, 64);
    if (ov < v || (ov == v && os < bs)) { v = ov; bs = os; bl = ol; }
  }
  int lam = __builtin_amdgcn_readfirstlane(bl);

  // ---- reconstruction: 86 chunk hops, prefetched rows, bits stored per hop ----
  const size_t ob = (size_t)b * T_STEPS;
  unsigned row = tbf[85 * 64 + lane];
  for (int c = 85; c >= 0; --c) {
    unsigned nrow = 0;
    if (c > 0) nrow = tbf[(c - 1) * 64 + lane];          // prefetch (addr indep of lam)
    const unsigned w = (unsigned)__builtin_amdgcn_readlane((int)row, lam);
    const int nb = (c == 85) ? 8 : 24;
    if (lane < nb) out[ob + c * 24 + lane] = (float)((w >> (6 + lane)) & 1u);
    lam = (int)(w & 63u);
    row = nrow;
  }
}

extern "C" void kernel_launch(void* const* d_in, const int* in_sizes, int n_in,
                              void* d_out, int out_size, void* d_ws, size_t ws_size,
                              hipStream_t stream) {
  const float* in = (const float*)d_in[0];
  float* out = (float*)d_out;
  (void)in_sizes; (void)n_in; (void)out_size; (void)d_ws; (void)ws_size;
  viterbi_kernel<<<dim3(512), dim3(64), 0, stream>>>(in, out);
}